// Round 15
// baseline (43.451 us; speedup 1.0000x reference)
//
#include <hip/hip_runtime.h>
#include <math.h>

constexpr int Bb = 4, Cc = 64, Hh = 256, Ww = 256;
constexpr int RR = 8;            // output rows per block (amp = 10/8 = 1.25x)
constexpr int CS = 4;            // channel split (16 ch per block)
constexpr int NSTRIP = Hh / RR;  // 32
constexpr int NPX = Bb * Hh * Ww;       // 262144 output pixels
constexpr int NPX4 = NPX / 4;           // 65536 float4s

#define LOG2E 1.44269504088896340736f
#define LN2   0.69314718055994530942f

__device__ __forceinline__ unsigned int fenc(float f) {
  unsigned int u = __float_as_uint(f);
  return (u & 0x80000000u) ? ~u : (u | 0x80000000u);
}
__device__ __forceinline__ float fdec(unsigned int k) {
  return __uint_as_float((k & 0x80000000u) ? (k ^ 0x80000000u) : ~k);
}

// entropy = ln(s) - ws/s, s = 3x3 box of e^v, ws = 3x3 box of v*e^v
// (shift-invariant softmax entropy; N(0,1) inputs so e^v safe in fp32).
// Normalization is affine-invariant, so raw channel sums are normalized.
//
// Grid: b(4) x strip(32) x cs(4) = 512 blocks, block (64,8) -> 4096 waves.
// Each block: RR=8 output rows x 16 channels (2 per ty, rolled cc loop).
// Halo amplification (RR+2)/RR = 1.25x (vs 1.5x at RR=4): -17% bytes+exps.
// 3-slot ring of horizontal sums; rows streamed (compiler hoists loads in
// the unrolled j-loop). Two-phase LDS reduce keeps LDS at 32KB.
//   DST=0: non-atomic store of channel-quarter partial into pw[cs][...]
//   DST=1: atomicAdd into e (fallback; e pre-zeroed)
// NOTE: plain __launch_bounds__(512) only — min-waves hints spill (r6/r7).
template <int DST>
__global__ __launch_bounds__(512) void entropy_kernel(const float* __restrict__ x,
                                                      float* __restrict__ out) {
  const int bx = blockIdx.x;
  const int cs = bx & 3;
  const int strip = (bx >> 2) & (NSTRIP - 1);
  const int b = bx >> 7;
  const int r0 = strip * RR;
  const int tx = threadIdx.x;   // 0..63
  const int ty = threadIdx.y;   // 0..7
  const int w0 = tx * 4;

  const size_t planeStride = (size_t)Hh * Ww;
  const float* xb = x + ((size_t)b * Cc + cs * 16 + ty * 2) * planeStride + w0;

  float acc[RR][4];
#pragma unroll
  for (int o = 0; o < RR; ++o)
#pragma unroll
    for (int i = 0; i < 4; ++i) acc[o][i] = 0.f;

#pragma unroll 1
  for (int cc = 0; cc < 2; ++cc) {
    const float* plane = xb + (size_t)cc * planeStride;

    float ha[3][4], hb[3][4];
#pragma unroll
    for (int j = 0; j < RR + 2; ++j) {
      const int row = r0 - 1 + j;
      float4 v = make_float4(0.f, 0.f, 0.f, 0.f);
      if (row >= 0 && row < Hh)
        v = *reinterpret_cast<const float4*>(plane + (size_t)row * Ww);
      const float* vp = &v.x;
      float a[4], bb4[4];
#pragma unroll
      for (int i = 0; i < 4; ++i) {
        float t = __builtin_amdgcn_exp2f(vp[i] * LOG2E);  // e^v
        a[i] = t;
        bb4[i] = vp[i] * t;                               // v * e^v
      }
      float la = __shfl_up(a[3], 1, 64);
      float lb = __shfl_up(bb4[3], 1, 64);
      float ra = __shfl_down(a[0], 1, 64);
      float rb = __shfl_down(bb4[0], 1, 64);
      la = (tx == 0) ? 1.f : la;   lb = (tx == 0) ? 0.f : lb;
      ra = (tx == 63) ? 1.f : ra;  rb = (tx == 63) ? 0.f : rb;
      const int s0 = j % 3;  // compile-time (loop unrolled)
      ha[s0][0] = la + a[0] + a[1];
      ha[s0][1] = a[0] + a[1] + a[2];
      ha[s0][2] = a[1] + a[2] + a[3];
      ha[s0][3] = a[2] + a[3] + ra;
      hb[s0][0] = lb + bb4[0] + bb4[1];
      hb[s0][1] = bb4[0] + bb4[1] + bb4[2];
      hb[s0][2] = bb4[1] + bb4[2] + bb4[3];
      hb[s0][3] = bb4[2] + bb4[3] + rb;
      if (j >= 2) {
        const int orow = j - 2;
#pragma unroll
        for (int i = 0; i < 4; ++i) {
          float s = ha[0][i] + ha[1][i] + ha[2][i];
          float w = hb[0][i] + hb[1][i] + hb[2][i];
          acc[orow][i] += LN2 * __builtin_amdgcn_logf(s) -
                          w * __builtin_amdgcn_rcpf(s);
        }
      }
    }
  }

  // Two-phase reduce of the 8 ty groups (32 KiB LDS): rows 0-3, then 4-7.
  __shared__ float red[8][4][4][64];
#pragma unroll 1
  for (int ph = 0; ph < 2; ++ph) {
    if (ph) __syncthreads();
#pragma unroll
    for (int o2 = 0; o2 < 4; ++o2)
#pragma unroll
      for (int i = 0; i < 4; ++i) red[ty][o2][i][tx] = acc[ph * 4 + o2][i];
    __syncthreads();
    if (ty < 4) {
      const int o = ph * 4 + ty;
      const size_t px = (size_t)(b * Hh + r0 + o) * Ww + w0;
      float vsum[4];
#pragma unroll
      for (int i = 0; i < 4; ++i) {
        float t = 0.f;
#pragma unroll
        for (int g = 0; g < 8; ++g) t += red[g][ty][i][tx];
        vsum[i] = t;
      }
      if (DST == 0) {
        *reinterpret_cast<float4*>(out + (size_t)cs * NPX + px) =
            make_float4(vsum[0], vsum[1], vsum[2], vsum[3]);
      } else {
#pragma unroll
        for (int i = 0; i < 4; ++i) atomicAdd(out + px + i, vsum[i]);
      }
    }
  }
}

// ws path K2: combine the 4 channel-quarter partials, write e, emit
// per-block min/max partials (every slot written -> no init needed).
// Grid 256 x 256 threads, one float4 per thread. Batch = bx>>6.
__global__ __launch_bounds__(256) void combine_minmax(const float* __restrict__ pw,
                                                      float* __restrict__ e,
                                                      float* __restrict__ pm) {
  const int t = blockIdx.x * 256 + threadIdx.x;
  float4 v0 = reinterpret_cast<const float4*>(pw)[t];
  float4 v1 = reinterpret_cast<const float4*>(pw + (size_t)NPX)[t];
  float4 v2 = reinterpret_cast<const float4*>(pw + 2 * (size_t)NPX)[t];
  float4 v3 = reinterpret_cast<const float4*>(pw + 3 * (size_t)NPX)[t];
  float4 v = make_float4(v0.x + v1.x + v2.x + v3.x, v0.y + v1.y + v2.y + v3.y,
                         v0.z + v1.z + v2.z + v3.z, v0.w + v1.w + v2.w + v3.w);
  reinterpret_cast<float4*>(e)[t] = v;

  float mn = fminf(fminf(v.x, v.y), fminf(v.z, v.w));
  float mx = fmaxf(fmaxf(v.x, v.y), fmaxf(v.z, v.w));
#pragma unroll
  for (int off = 32; off > 0; off >>= 1) {
    mn = fminf(mn, __shfl_down(mn, off, 64));
    mx = fmaxf(mx, __shfl_down(mx, off, 64));
  }
  __shared__ float smn[4], smx[4];
  const int wave = threadIdx.x >> 6;
  if ((threadIdx.x & 63) == 0) { smn[wave] = mn; smx[wave] = mx; }
  __syncthreads();
  if (threadIdx.x == 0) {
    pm[blockIdx.x]       = fminf(fminf(smn[0], smn[1]), fminf(smn[2], smn[3]));
    pm[256 + blockIdx.x] = fmaxf(fmaxf(smx[0], smx[1]), fmaxf(smx[2], smx[3]));
  }
}

// ws path K3: reduce this batch's 64 min/max partials in-wave (redundant per
// wave, cheap), then normalize. Grid 256 x 256, one float4 per thread.
__global__ __launch_bounds__(256) void norm_ws(float* __restrict__ e,
                                               const float* __restrict__ pm) {
  const int b = blockIdx.x >> 6;
  const int lane = threadIdx.x & 63;
  float mn = pm[b * 64 + lane];
  float mx = pm[256 + b * 64 + lane];
#pragma unroll
  for (int off = 32; off > 0; off >>= 1) {
    mn = fminf(mn, __shfl_down(mn, off, 64));
    mx = fmaxf(mx, __shfl_down(mx, off, 64));
  }
  mn = __shfl(mn, 0, 64);
  mx = __shfl(mx, 0, 64);
  const float inv = 1.0f / fmaxf(mx - mn, 1e-6f);

  const int t = blockIdx.x * 256 + threadIdx.x;
  float4 v = reinterpret_cast<float4*>(e)[t];
  v.x = (v.x - mn) * inv;
  v.y = (v.y - mn) * inv;
  v.z = (v.z - mn) * inv;
  v.w = (v.w - mn) * inv;
  reinterpret_cast<float4*>(e)[t] = v;
}

// Fallback path kernels (atomics + memset) — used only if ws is tiny.
__global__ __launch_bounds__(256) void minmax_atomic(const float* __restrict__ e,
                                                     unsigned int* __restrict__ stats) {
  const int bx = blockIdx.x;
  const int b = bx >> 6;
  const float4 v = reinterpret_cast<const float4*>(
      e + (size_t)b * Hh * Ww + (bx & 63) * 1024)[threadIdx.x];
  float mn = fminf(fminf(v.x, v.y), fminf(v.z, v.w));
  float mx = fmaxf(fmaxf(v.x, v.y), fmaxf(v.z, v.w));
#pragma unroll
  for (int off = 32; off > 0; off >>= 1) {
    mn = fminf(mn, __shfl_down(mn, off, 64));
    mx = fmaxf(mx, __shfl_down(mx, off, 64));
  }
  __shared__ float smn[4], smx[4];
  const int wave = threadIdx.x >> 6;
  if ((threadIdx.x & 63) == 0) { smn[wave] = mn; smx[wave] = mx; }
  __syncthreads();
  if (threadIdx.x == 0) {
    atomicMin(&stats[b], fenc(fminf(fminf(smn[0], smn[1]), fminf(smn[2], smn[3]))));
    atomicMax(&stats[4 + b], fenc(fmaxf(fmaxf(smx[0], smx[1]), fmaxf(smx[2], smx[3]))));
  }
}

__global__ __launch_bounds__(256) void norm_atomic(float* __restrict__ e,
                                                   const unsigned int* __restrict__ stats) {
  const int t = blockIdx.x * 256 + threadIdx.x;
  const int b = t >> 14;
  const float mn = fdec(stats[b]);
  const float mx = fdec(stats[4 + b]);
  const float inv = 1.0f / fmaxf(mx - mn, 1e-6f);
  float4 v = reinterpret_cast<float4*>(e)[t];
  v.x = (v.x - mn) * inv;
  v.y = (v.y - mn) * inv;
  v.z = (v.z - mn) * inv;
  v.w = (v.w - mn) * inv;
  reinterpret_cast<float4*>(e)[t] = v;
}

extern "C" void kernel_launch(void* const* d_in, const int* in_sizes, int n_in,
                              void* d_out, int out_size, void* d_ws, size_t ws_size,
                              hipStream_t stream) {
  const float* x = (const float*)d_in[0];
  float* out = (float*)d_out;

  const size_t ws_needed = ((size_t)CS * NPX + 512) * sizeof(float);  // ~4.2 MB
  if (ws_size >= ws_needed) {
    float* pw = (float*)d_ws;                 // [CS][NPX] partials
    float* pm = pw + (size_t)CS * NPX;        // [256 min][256 max]
    entropy_kernel<0><<<dim3(Bb * NSTRIP * CS), dim3(64, 8), 0, stream>>>(x, pw);
    combine_minmax<<<dim3(NPX4 / 256), dim3(256), 0, stream>>>(pw, out, pm);
    norm_ws<<<dim3(NPX4 / 256), dim3(256), 0, stream>>>(out, pm);
  } else {
    unsigned int* stats = (unsigned int*)d_ws;  // 8 uints
    hipMemsetAsync(out, 0, (size_t)NPX * sizeof(float), stream);
    hipMemsetAsync(stats, 0xFF, 4 * sizeof(unsigned int), stream);
    hipMemsetAsync(stats + 4, 0x00, 4 * sizeof(unsigned int), stream);
    entropy_kernel<1><<<dim3(Bb * NSTRIP * CS), dim3(64, 8), 0, stream>>>(x, out);
    minmax_atomic<<<dim3(Bb * 64), dim3(256), 0, stream>>>(out, stats);
    norm_atomic<<<dim3(NPX4 / 256), dim3(256), 0, stream>>>(out, stats);
  }
}

// Round 16
// 30.660 us; speedup vs baseline: 1.4172x; 1.4172x over previous
//
#include <hip/hip_runtime.h>
#include <math.h>

constexpr int Bb = 4, Cc = 64, Hh = 256, Ww = 256;
constexpr int RR = 8;            // output rows per block (amp = 10/8 = 1.25x)
constexpr int CS = 4;            // channel split (16 ch per block)
constexpr int NSTRIP = Hh / RR;  // 32
constexpr int NPX = Bb * Hh * Ww;       // 262144 output pixels
constexpr int NPX4 = NPX / 4;           // 65536 float4s

#define LOG2E 1.44269504088896340736f
#define LN2   0.69314718055994530942f

__device__ __forceinline__ unsigned int fenc(float f) {
  unsigned int u = __float_as_uint(f);
  return (u & 0x80000000u) ? ~u : (u | 0x80000000u);
}
__device__ __forceinline__ float fdec(unsigned int k) {
  return __uint_as_float((k & 0x80000000u) ? (k ^ 0x80000000u) : ~k);
}

// entropy = ln(s) - ws/s, s = 3x3 box of e^v, ws = 3x3 box of v*e^v
// (shift-invariant softmax entropy; N(0,1) inputs so e^v safe in fp32).
// Normalization is affine-invariant, so raw channel sums are normalized.
//
// Grid: b(4) x strip(32) x cs(4) = 512 blocks, block (64,8) -> 4096 waves.
// Each block: RR=8 output rows x 16 channels (2 per ty, rolled cc loop).
// Halo amplification (RR+2)/RR = 1.25x (vs 1.5x at RR=4): -17% bytes+exps.
// Two-phase LDS reduce is HAND-UNROLLED: r15 used a rolled phase loop and
// `acc[ph*4+o2]` runtime indexing sent acc to scratch (63MB WRITE_SIZE,
// 3x slowdown — rule: runtime-indexed register arrays spill to local mem).
// All acc indices below are compile-time constants.
//   DST=0: non-atomic store of channel-quarter partial into pw[cs][...]
//   DST=1: atomicAdd into e (fallback; e pre-zeroed)
// NOTE: plain __launch_bounds__(512) only — min-waves hints spill (r6/r7).
template <int DST>
__global__ __launch_bounds__(512) void entropy_kernel(const float* __restrict__ x,
                                                      float* __restrict__ out) {
  const int bx = blockIdx.x;
  const int cs = bx & 3;
  const int strip = (bx >> 2) & (NSTRIP - 1);
  const int b = bx >> 7;
  const int r0 = strip * RR;
  const int tx = threadIdx.x;   // 0..63
  const int ty = threadIdx.y;   // 0..7
  const int w0 = tx * 4;

  const size_t planeStride = (size_t)Hh * Ww;
  const float* xb = x + ((size_t)b * Cc + cs * 16 + ty * 2) * planeStride + w0;

  float acc[RR][4];
#pragma unroll
  for (int o = 0; o < RR; ++o)
#pragma unroll
    for (int i = 0; i < 4; ++i) acc[o][i] = 0.f;

#pragma unroll 1
  for (int cc = 0; cc < 2; ++cc) {
    const float* plane = xb + (size_t)cc * planeStride;

    float ha[3][4], hb[3][4];
#pragma unroll
    for (int j = 0; j < RR + 2; ++j) {
      const int row = r0 - 1 + j;
      float4 v = make_float4(0.f, 0.f, 0.f, 0.f);
      if (row >= 0 && row < Hh)
        v = *reinterpret_cast<const float4*>(plane + (size_t)row * Ww);
      const float* vp = &v.x;
      float a[4], bb4[4];
#pragma unroll
      for (int i = 0; i < 4; ++i) {
        float t = __builtin_amdgcn_exp2f(vp[i] * LOG2E);  // e^v
        a[i] = t;
        bb4[i] = vp[i] * t;                               // v * e^v
      }
      float la = __shfl_up(a[3], 1, 64);
      float lb = __shfl_up(bb4[3], 1, 64);
      float ra = __shfl_down(a[0], 1, 64);
      float rb = __shfl_down(bb4[0], 1, 64);
      la = (tx == 0) ? 1.f : la;   lb = (tx == 0) ? 0.f : lb;
      ra = (tx == 63) ? 1.f : ra;  rb = (tx == 63) ? 0.f : rb;
      const int s0 = j % 3;  // compile-time (loop unrolled)
      ha[s0][0] = la + a[0] + a[1];
      ha[s0][1] = a[0] + a[1] + a[2];
      ha[s0][2] = a[1] + a[2] + a[3];
      ha[s0][3] = a[2] + a[3] + ra;
      hb[s0][0] = lb + bb4[0] + bb4[1];
      hb[s0][1] = bb4[0] + bb4[1] + bb4[2];
      hb[s0][2] = bb4[1] + bb4[2] + bb4[3];
      hb[s0][3] = bb4[2] + bb4[3] + rb;
      if (j >= 2) {
        const int orow = j - 2;   // compile-time (loop unrolled)
#pragma unroll
        for (int i = 0; i < 4; ++i) {
          float s = ha[0][i] + ha[1][i] + ha[2][i];
          float w = hb[0][i] + hb[1][i] + hb[2][i];
          acc[orow][i] += LN2 * __builtin_amdgcn_logf(s) -
                          w * __builtin_amdgcn_rcpf(s);
        }
      }
    }
  }

  // Two-phase reduce of the 8 ty groups (32 KiB LDS), hand-unrolled so all
  // acc indices are static.
  __shared__ float red[8][4][4][64];

  // ---- phase 0: output rows 0..3 ----
#pragma unroll
  for (int o2 = 0; o2 < 4; ++o2)
#pragma unroll
    for (int i = 0; i < 4; ++i) red[ty][o2][i][tx] = acc[o2][i];
  __syncthreads();
  if (ty < 4) {
    const size_t px = (size_t)(b * Hh + r0 + ty) * Ww + w0;
    float vsum[4];
#pragma unroll
    for (int i = 0; i < 4; ++i) {
      float t = 0.f;
#pragma unroll
      for (int g = 0; g < 8; ++g) t += red[g][ty][i][tx];
      vsum[i] = t;
    }
    if (DST == 0) {
      *reinterpret_cast<float4*>(out + (size_t)cs * NPX + px) =
          make_float4(vsum[0], vsum[1], vsum[2], vsum[3]);
    } else {
#pragma unroll
      for (int i = 0; i < 4; ++i) atomicAdd(out + px + i, vsum[i]);
    }
  }
  __syncthreads();

  // ---- phase 1: output rows 4..7 ----
#pragma unroll
  for (int o2 = 0; o2 < 4; ++o2)
#pragma unroll
    for (int i = 0; i < 4; ++i) red[ty][o2][i][tx] = acc[4 + o2][i];
  __syncthreads();
  if (ty < 4) {
    const size_t px = (size_t)(b * Hh + r0 + 4 + ty) * Ww + w0;
    float vsum[4];
#pragma unroll
    for (int i = 0; i < 4; ++i) {
      float t = 0.f;
#pragma unroll
      for (int g = 0; g < 8; ++g) t += red[g][ty][i][tx];
      vsum[i] = t;
    }
    if (DST == 0) {
      *reinterpret_cast<float4*>(out + (size_t)cs * NPX + px) =
          make_float4(vsum[0], vsum[1], vsum[2], vsum[3]);
    } else {
#pragma unroll
      for (int i = 0; i < 4; ++i) atomicAdd(out + px + i, vsum[i]);
    }
  }
}

// ws path K2: combine the 4 channel-quarter partials, write e, emit
// per-block min/max partials (every slot written -> no init needed).
// Grid 256 x 256 threads, one float4 per thread. Batch = bx>>6.
__global__ __launch_bounds__(256) void combine_minmax(const float* __restrict__ pw,
                                                      float* __restrict__ e,
                                                      float* __restrict__ pm) {
  const int t = blockIdx.x * 256 + threadIdx.x;
  float4 v0 = reinterpret_cast<const float4*>(pw)[t];
  float4 v1 = reinterpret_cast<const float4*>(pw + (size_t)NPX)[t];
  float4 v2 = reinterpret_cast<const float4*>(pw + 2 * (size_t)NPX)[t];
  float4 v3 = reinterpret_cast<const float4*>(pw + 3 * (size_t)NPX)[t];
  float4 v = make_float4(v0.x + v1.x + v2.x + v3.x, v0.y + v1.y + v2.y + v3.y,
                         v0.z + v1.z + v2.z + v3.z, v0.w + v1.w + v2.w + v3.w);
  reinterpret_cast<float4*>(e)[t] = v;

  float mn = fminf(fminf(v.x, v.y), fminf(v.z, v.w));
  float mx = fmaxf(fmaxf(v.x, v.y), fmaxf(v.z, v.w));
#pragma unroll
  for (int off = 32; off > 0; off >>= 1) {
    mn = fminf(mn, __shfl_down(mn, off, 64));
    mx = fmaxf(mx, __shfl_down(mx, off, 64));
  }
  __shared__ float smn[4], smx[4];
  const int wave = threadIdx.x >> 6;
  if ((threadIdx.x & 63) == 0) { smn[wave] = mn; smx[wave] = mx; }
  __syncthreads();
  if (threadIdx.x == 0) {
    pm[blockIdx.x]       = fminf(fminf(smn[0], smn[1]), fminf(smn[2], smn[3]));
    pm[256 + blockIdx.x] = fmaxf(fmaxf(smx[0], smx[1]), fmaxf(smx[2], smx[3]));
  }
}

// ws path K3: reduce this batch's 64 min/max partials in-wave (redundant per
// wave, cheap), then normalize. Grid 256 x 256, one float4 per thread.
__global__ __launch_bounds__(256) void norm_ws(float* __restrict__ e,
                                               const float* __restrict__ pm) {
  const int b = blockIdx.x >> 6;
  const int lane = threadIdx.x & 63;
  float mn = pm[b * 64 + lane];
  float mx = pm[256 + b * 64 + lane];
#pragma unroll
  for (int off = 32; off > 0; off >>= 1) {
    mn = fminf(mn, __shfl_down(mn, off, 64));
    mx = fmaxf(mx, __shfl_down(mx, off, 64));
  }
  mn = __shfl(mn, 0, 64);
  mx = __shfl(mx, 0, 64);
  const float inv = 1.0f / fmaxf(mx - mn, 1e-6f);

  const int t = blockIdx.x * 256 + threadIdx.x;
  float4 v = reinterpret_cast<float4*>(e)[t];
  v.x = (v.x - mn) * inv;
  v.y = (v.y - mn) * inv;
  v.z = (v.z - mn) * inv;
  v.w = (v.w - mn) * inv;
  reinterpret_cast<float4*>(e)[t] = v;
}

// Fallback path kernels (atomics + memset) — used only if ws is tiny.
__global__ __launch_bounds__(256) void minmax_atomic(const float* __restrict__ e,
                                                     unsigned int* __restrict__ stats) {
  const int bx = blockIdx.x;
  const int b = bx >> 6;
  const float4 v = reinterpret_cast<const float4*>(
      e + (size_t)b * Hh * Ww + (bx & 63) * 1024)[threadIdx.x];
  float mn = fminf(fminf(v.x, v.y), fminf(v.z, v.w));
  float mx = fmaxf(fmaxf(v.x, v.y), fmaxf(v.z, v.w));
#pragma unroll
  for (int off = 32; off > 0; off >>= 1) {
    mn = fminf(mn, __shfl_down(mn, off, 64));
    mx = fmaxf(mx, __shfl_down(mx, off, 64));
  }
  __shared__ float smn[4], smx[4];
  const int wave = threadIdx.x >> 6;
  if ((threadIdx.x & 63) == 0) { smn[wave] = mn; smx[wave] = mx; }
  __syncthreads();
  if (threadIdx.x == 0) {
    atomicMin(&stats[b], fenc(fminf(fminf(smn[0], smn[1]), fminf(smn[2], smn[3]))));
    atomicMax(&stats[4 + b], fenc(fmaxf(fmaxf(smx[0], smx[1]), fmaxf(smx[2], smx[3]))));
  }
}

__global__ __launch_bounds__(256) void norm_atomic(float* __restrict__ e,
                                                   const unsigned int* __restrict__ stats) {
  const int t = blockIdx.x * 256 + threadIdx.x;
  const int b = t >> 14;
  const float mn = fdec(stats[b]);
  const float mx = fdec(stats[4 + b]);
  const float inv = 1.0f / fmaxf(mx - mn, 1e-6f);
  float4 v = reinterpret_cast<float4*>(e)[t];
  v.x = (v.x - mn) * inv;
  v.y = (v.y - mn) * inv;
  v.z = (v.z - mn) * inv;
  v.w = (v.w - mn) * inv;
  reinterpret_cast<float4*>(e)[t] = v;
}

extern "C" void kernel_launch(void* const* d_in, const int* in_sizes, int n_in,
                              void* d_out, int out_size, void* d_ws, size_t ws_size,
                              hipStream_t stream) {
  const float* x = (const float*)d_in[0];
  float* out = (float*)d_out;

  const size_t ws_needed = ((size_t)CS * NPX + 512) * sizeof(float);  // ~4.2 MB
  if (ws_size >= ws_needed) {
    float* pw = (float*)d_ws;                 // [CS][NPX] partials
    float* pm = pw + (size_t)CS * NPX;        // [256 min][256 max]
    entropy_kernel<0><<<dim3(Bb * NSTRIP * CS), dim3(64, 8), 0, stream>>>(x, pw);
    combine_minmax<<<dim3(NPX4 / 256), dim3(256), 0, stream>>>(pw, out, pm);
    norm_ws<<<dim3(NPX4 / 256), dim3(256), 0, stream>>>(out, pm);
  } else {
    unsigned int* stats = (unsigned int*)d_ws;  // 8 uints
    hipMemsetAsync(out, 0, (size_t)NPX * sizeof(float), stream);
    hipMemsetAsync(stats, 0xFF, 4 * sizeof(unsigned int), stream);
    hipMemsetAsync(stats + 4, 0x00, 4 * sizeof(unsigned int), stream);
    entropy_kernel<1><<<dim3(Bb * NSTRIP * CS), dim3(64, 8), 0, stream>>>(x, out);
    minmax_atomic<<<dim3(Bb * 64), dim3(256), 0, stream>>>(out, stats);
    norm_atomic<<<dim3(NPX4 / 256), dim3(256), 0, stream>>>(out, stats);
  }
}